// Round 1
// 259.070 us; speedup vs baseline: 1.0248x; 1.0248x over previous
//
#include <hip/hip_runtime.h>
#include <cstdint>
#include <cstddef>

typedef unsigned short u16;
typedef __bf16 bf16x8 __attribute__((ext_vector_type(8)));
typedef float f32x4 __attribute__((ext_vector_type(4)));

// fp32 -> bf16 round-to-nearest-even (inputs finite)
__device__ inline u16 f2b(float f) {
    uint32_t u = __builtin_bit_cast(uint32_t, f);
    u += 0x7FFFu + ((u >> 16) & 1u);
    return (u16)(u >> 16);
}

// async global->LDS DMA, 16B per lane; lds dst is wave-uniform base + lane*16
__device__ inline void gl2lds16(const u16* g, u16* l) {
    __builtin_amdgcn_global_load_lds(
        (const __attribute__((address_space(1))) void*)g,
        (__attribute__((address_space(3))) void*)l, 16, 0, 0);
}

template<int N> __device__ __forceinline__ void waitvm() {
    asm volatile("s_waitcnt vmcnt(%0)" :: "n"(N) : "memory");
}

// ---------------- prep: fp32 -> bf16 convert (x) ----------------
__global__ void convert_x_kernel(const float* __restrict__ x, u16* __restrict__ xb) {
    size_t i = ((size_t)blockIdx.x * 256 + threadIdx.x) * 4;
    float4 v = *(const float4*)(x + i);
    uint2 pack;
    pack.x = (uint32_t)f2b(v.x) | ((uint32_t)f2b(v.y) << 16);
    pack.y = (uint32_t)f2b(v.z) | ((uint32_t)f2b(v.w) << 16);
    *(uint2*)(xb + i) = pack;
}

// ---------------- prep: all 3 weights [k][n] fp32 -> [n][k] bf16, z-fused ----
__global__ void transpose_w_kernel(const float* __restrict__ Wq,
                                   const float* __restrict__ Wk,
                                   const float* __restrict__ Wv,
                                   u16* __restrict__ QKWT, u16* __restrict__ WvT) {
    __shared__ u16 t[32][33];
    const int z = blockIdx.z;
    const float* W = (z == 0) ? Wq : ((z == 1) ? Wk : Wv);
    u16* dst = (z == 0) ? QKWT : ((z == 1) ? QKWT + 1024 * 1024 : WvT);
    const float scale = (z == 0) ? 0.03125f : 1.0f;  // fold 1/sqrt(1024) into Wq
    const int bx = blockIdx.x * 32;  // n origin
    const int by = blockIdx.y * 32;  // k origin
    const int tx = threadIdx.x, ty = threadIdx.y;
    #pragma unroll
    for (int r = 0; r < 32; r += 8)
        t[ty + r][tx] = f2b(W[(size_t)(by + ty + r) * 1024 + bx + tx] * scale);
    __syncthreads();
    #pragma unroll
    for (int r = 0; r < 32; r += 8)
        dst[(size_t)(bx + ty + r) * 1024 + (by + tx)] = t[tx][ty + r];
}

// ============================================================================
// 256-row tile NT GEMM, counted-vmcnt pipeline (T3+T4+T5).
//   C = A (M x K) * B^T, B stored [N][K].
//   BM = 256, BN = NFRAG*64, BK = 32. 512 threads = 8 waves as 2(M) x 4(N);
//   per-wave output 128 x (NFRAG*16) = 8 x NFRAG fragments of 16x16.
//   LDS: 4-buffer ring (stage distance 3), raw s_barrier, vmcnt never drained
//   to 0 in the main loop (steady state: 3 tiles = 3*LPT loads in flight).
//   BK=32 => LDS row stride 64B => each frag ds_read_b128 covers a contiguous
//   1KB block per wave => bank-conflict-free without swizzle (gload_lds-safe).
// EPI 0: C bf16 = acc
// EPI 2: causal mask + exp -> P bf16, atomicAdd row sums into lrow
// EPI 3: C fp32 = acc / lrow[row]
// Requires Kloc % 32 == 0 and Kloc >= 96 (NT >= 3).
// ============================================================================
template<int NFRAG, int EPI>
__device__ __forceinline__ void gemm256(
    u16* __restrict__ smem,
    const u16* __restrict__ A, int lda,
    const u16* __restrict__ B, int ldb,
    char* __restrict__ Cb, int ldc,
    int m0, int n0, int Kloc, float* __restrict__ lrow) {
    constexpr int BK  = 32;
    constexpr int ASZ = 256 * BK;          // 8192 u16 per A buffer
    constexpr int BSZ = NFRAG * 64 * BK;   // u16 per B buffer
    constexpr int LPT = 2 + NFRAG / 2;     // gload_lds per thread per K-tile

    const int tid  = threadIdx.x;
    const int lane = tid & 63, wave = tid >> 6;
    const int wm = wave >> 2, wn = wave & 3;
    const int fl = lane & 15, fh = lane >> 4;

    // staging: linear LDS, per-lane global src. idx = j*512 + tid covers
    // 16B chunks; row = idx>>2, koff = (idx&3)*8 elems; LDS off = idx*16B.
    const int r0 = tid >> 2;
    const int ko = (tid & 3) * 8;
    const u16* Ap0 = A + (size_t)(m0 + r0) * lda + ko;
    const u16* Ap1 = Ap0 + (size_t)128 * lda;
    const u16* Bp0 = B + (size_t)(n0 + r0) * ldb + ko;
    const u16* Bp1 = Bp0 + (size_t)128 * ldb;      // only when NFRAG==4

    u16* const Ab = smem;                  // 4 x ASZ
    u16* const Bb = smem + 4 * ASZ;        // 4 x BSZ

    auto stage = [&](int t) {
        const int buf = t & 3;
        const int k0  = t * BK;
        u16* Ad = Ab + buf * ASZ + wave * 512;
        gl2lds16(Ap0 + k0, Ad);
        gl2lds16(Ap1 + k0, Ad + 4096);
        u16* Bd = Bb + buf * BSZ + wave * 512;
        gl2lds16(Bp0 + k0, Bd);
        if constexpr (NFRAG == 4) gl2lds16(Bp1 + k0, Bd + 4096);
    };

    const f32x4 vzero = {0.f, 0.f, 0.f, 0.f};
    f32x4 acc[8][NFRAG];
    #pragma unroll
    for (int i = 0; i < 8; ++i)
        #pragma unroll
        for (int j = 0; j < NFRAG; ++j) acc[i][j] = vzero;

    const int NT = Kloc >> 5;
    stage(0); stage(1); stage(2);

    for (int t = 0; t < NT; ++t) {
        if (t + 3 < NT) stage(t + 3);
        // wait until <= nafter tiles (the newest) remain in flight => tile t landed
        const int nafter = (NT - 1 - t) < 3 ? (NT - 1 - t) : 3;
        if (nafter == 3)      waitvm<3 * LPT>();
        else if (nafter == 2) waitvm<2 * LPT>();
        else if (nafter == 1) waitvm<LPT>();
        else                  waitvm<0>();
        __builtin_amdgcn_s_barrier();          // everyone's tile-t DMA visible
        asm volatile("" ::: "memory");

        const u16* At = Ab + (t & 3) * ASZ;
        const u16* Bt = Bb + (t & 3) * BSZ;
        bf16x8 af[8], bfr[NFRAG];
        #pragma unroll
        for (int mt = 0; mt < 8; ++mt)
            af[mt] = *(const bf16x8*)&At[(wm * 128 + mt * 16 + fl) * BK + fh * 8];
        #pragma unroll
        for (int nt = 0; nt < NFRAG; ++nt)
            bfr[nt] = *(const bf16x8*)&Bt[(wn * (NFRAG * 16) + nt * 16 + fl) * BK + fh * 8];

        __builtin_amdgcn_s_setprio(1);
        #pragma unroll
        for (int mt = 0; mt < 8; ++mt)
            #pragma unroll
            for (int nt = 0; nt < NFRAG; ++nt)
                acc[mt][nt] = __builtin_amdgcn_mfma_f32_16x16x32_bf16(
                    af[mt], bfr[nt], acc[mt][nt], 0, 0, 0);
        __builtin_amdgcn_s_setprio(0);

        asm volatile("s_waitcnt lgkmcnt(0)" ::: "memory");  // all reads of buf t done
        __builtin_amdgcn_s_barrier();          // safe to overwrite buf (t&3) next
        asm volatile("" ::: "memory");
    }

    const int rbase = m0 + wm * 128 + fh * 4;
    const int cbase = n0 + wn * (NFRAG * 16) + fl;
    if constexpr (EPI == 0) {
        u16* Cp = (u16*)Cb;
        #pragma unroll
        for (int mt = 0; mt < 8; ++mt)
            #pragma unroll
            for (int nt = 0; nt < NFRAG; ++nt)
                #pragma unroll
                for (int r = 0; r < 4; ++r)
                    Cp[(size_t)(rbase + mt * 16 + r) * ldc + cbase + nt * 16] =
                        f2b(acc[mt][nt][r]);
    } else if constexpr (EPI == 2) {
        u16* Cp = (u16*)Cb;
        #pragma unroll
        for (int mt = 0; mt < 8; ++mt)
            #pragma unroll
            for (int r = 0; r < 4; ++r) {
                const int row = rbase + mt * 16 + r;
                float part = 0.f;
                #pragma unroll
                for (int nt = 0; nt < NFRAG; ++nt) {
                    const int col = cbase + nt * 16;
                    float p = (col <= row) ? __expf(acc[mt][nt][r]) : 0.f;
                    part += p;
                    Cp[(size_t)row * ldc + col] = f2b(p);
                }
                #pragma unroll
                for (int off = 1; off < 16; off <<= 1)
                    part += __shfl_xor(part, off, 64);
                if (fl == 0) atomicAdd(lrow + row, part);
            }
    } else {
        float* Cp = (float*)Cb;
        #pragma unroll
        for (int mt = 0; mt < 8; ++mt)
            #pragma unroll
            for (int r = 0; r < 4; ++r) {
                const int row = rbase + mt * 16 + r;
                const float inv = 1.0f / lrow[row];
                #pragma unroll
                for (int nt = 0; nt < NFRAG; ++nt)
                    Cp[(size_t)row * ldc + cbase + nt * 16] = acc[mt][nt][r] * inv;
            }
    }
}

// ---- merged projection dispatch: QK (256 blocks) + V^T (128 blocks) --------
__global__ __launch_bounds__(512, 2)
void proj_kernel(const u16* __restrict__ xb, const u16* __restrict__ QKWT,
                 const u16* __restrict__ WvT, u16* __restrict__ QK,
                 u16* __restrict__ Vt) {
    __shared__ __align__(16) u16 smem[65536];   // 128 KB: 4xA + 4xB buffers
    const int bid = blockIdx.x;
    const u16 *A, *B;
    char* C;
    int ldc, m0, n0;
    if (bid < 256) {             // QK: [8192][2048] = xb @ QKWT^T
        const int it = bid >> 3, jt = bid & 7;
        A = xb;  B = QKWT;  C = (char*)QK;  ldc = 2048;
        m0 = it * 256;  n0 = jt * 256;
    } else {                     // V^T: [1024][8192] = WvT @ xb^T
        const int b = bid - 256;
        const int it = b >> 5, jt = b & 31;
        A = WvT;  B = xb;  C = (char*)Vt;  ldc = 8192;
        m0 = it * 256;  n0 = jt * 256;
    }
    gemm256<4, 0>(smem, A, 1024, B, 1024, C, ldc, m0, n0, 1024, nullptr);
}

// ---- scores: compact triangular grid (36 x 256^2 tiles), P = exp, row sums --
__global__ __launch_bounds__(512, 2)
void scores_kernel(const u16* __restrict__ QK, u16* __restrict__ P,
                   float* __restrict__ l) {
    __shared__ __align__(16) u16 smem[65536];
    const int t = blockIdx.x, z = blockIdx.y;
    int it = (int)((sqrtf(8.0f * t + 1.0f) - 1.0f) * 0.5f);
    while ((it + 1) * (it + 2) / 2 <= t) ++it;
    while (it * (it + 1) / 2 > t) --it;
    const int jt = t - it * (it + 1) / 2;
    const u16* Qz = QK + (size_t)z * 2048 * 2048;  // Q cols [0,1024)
    const u16* Kz = Qz + 1024;                     // K cols [1024,2048)
    u16* Pz = P + (size_t)z * 2048 * 2048;
    gemm256<4, 2>(smem, Qz, 2048, Kz, 2048, (char*)Pz, 2048,
                  it * 256, jt * 256, 1024, l + (size_t)z * 2048);
}

// ---- output: O = (P/l) @ V, 256x128 tiles, causal K-extent, 256 blocks -----
__global__ __launch_bounds__(512, 2)
void out_kernel(const u16* __restrict__ P, const u16* __restrict__ Vt,
                float* __restrict__ out, float* __restrict__ l) {
    __shared__ __align__(16) u16 smem[49152];   // 96 KB: 4xA(16K) + 4xB(8K)
    const int jt = blockIdx.x;              // 0..7  (N = 1024 / 128)
    const int it = 7 - (int)blockIdx.y;     // heavy first (Kloc = (it+1)*256)
    const int z = blockIdx.z;
    gemm256<2, 3>(smem, P + (size_t)z * 2048 * 2048, 2048,
                  Vt + (size_t)z * 2048, 8192,
                  (char*)(out + (size_t)z * 2048 * 1024), 1024,
                  it * 256, jt * 128, (it + 1) * 256, l + (size_t)z * 2048);
}

extern "C" void kernel_launch(void* const* d_in, const int* in_sizes, int n_in,
                              void* d_out, int out_size, void* d_ws, size_t ws_size,
                              hipStream_t stream) {
    (void)in_sizes; (void)n_in; (void)out_size; (void)ws_size;
    const float* x  = (const float*)d_in[0];
    const float* Wq = (const float*)d_in[1];
    const float* Wk = (const float*)d_in[2];
    const float* Wv = (const float*)d_in[3];
    float* out = (float*)d_out;

    const size_t MB = 1u << 20;
    char* ws = (char*)d_ws;
    u16* xb   = (u16*)(ws);              // [8192][1024] bf16       16 MB
    u16* QKWT = (u16*)(ws + 16 * MB);    // [2048][1024] (WqT*s | WkT) 4 MB
    u16* WvT  = (u16*)(ws + 20 * MB);    // [1024][1024]             2 MB
    u16* QK   = (u16*)(ws + 22 * MB);    // [8192][2048] (Q|K)      32 MB
    u16* Vt   = (u16*)(ws + 54 * MB);    // V^T [1024][8192]        16 MB
    u16* P    = (u16*)(ws + 70 * MB);    // exp(S) [4][2048][2048]  32 MB
    float* l  = (float*)(ws + 102 * MB); // row sums [4][2048]      32 KB

    hipMemsetAsync(l, 0, 8192 * sizeof(float), stream);
    convert_x_kernel<<<8192, 256, 0, stream>>>(x, xb);
    transpose_w_kernel<<<dim3(32, 32, 3), dim3(32, 8), 0, stream>>>(Wq, Wk, Wv, QKWT, WvT);

    proj_kernel<<<384, 512, 0, stream>>>(xb, QKWT, WvT, QK, Vt);
    scores_kernel<<<dim3(36, 4), 512, 0, stream>>>(QK, P, l);
    out_kernel<<<dim3(8, 8, 4), 512, 0, stream>>>(P, Vt, out, l);
}

// Round 2
// 235.830 us; speedup vs baseline: 1.1258x; 1.0985x over previous
//
#include <hip/hip_runtime.h>
#include <cstdint>
#include <cstddef>
#include <type_traits>

typedef unsigned short u16;
typedef __bf16 bf16x8 __attribute__((ext_vector_type(8)));
typedef float f32x4 __attribute__((ext_vector_type(4)));

// fp32 -> bf16 round-to-nearest-even (inputs finite)
__device__ inline u16 f2b(float f) {
    uint32_t u = __builtin_bit_cast(uint32_t, f);
    u += 0x7FFFu + ((u >> 16) & 1u);
    return (u16)(u >> 16);
}

// async global->LDS DMA, 16B per lane; lds dst is wave-uniform base + lane*16
__device__ inline void gl2lds16(const u16* g, u16* l) {
    __builtin_amdgcn_global_load_lds(
        (const __attribute__((address_space(1))) void*)g,
        (__attribute__((address_space(3))) void*)l, 16, 0, 0);
}

template<int N> __device__ __forceinline__ void waitvm() {
    asm volatile("s_waitcnt vmcnt(%0)" :: "n"(N) : "memory");
}
__device__ __forceinline__ void bar() {
    asm volatile("" ::: "memory");
    __builtin_amdgcn_s_barrier();
    asm volatile("" ::: "memory");
}

// ---------------- prep: fp32 -> bf16 convert (x) ----------------
__global__ void convert_x_kernel(const float* __restrict__ x, u16* __restrict__ xb) {
    size_t i = ((size_t)blockIdx.x * 256 + threadIdx.x) * 4;
    float4 v = *(const float4*)(x + i);
    uint2 pack;
    pack.x = (uint32_t)f2b(v.x) | ((uint32_t)f2b(v.y) << 16);
    pack.y = (uint32_t)f2b(v.z) | ((uint32_t)f2b(v.w) << 16);
    *(uint2*)(xb + i) = pack;
}

// ---------------- prep: all 3 weights [k][n] fp32 -> [n][k] bf16, z-fused ----
__global__ void transpose_w_kernel(const float* __restrict__ Wq,
                                   const float* __restrict__ Wk,
                                   const float* __restrict__ Wv,
                                   u16* __restrict__ QKWT, u16* __restrict__ WvT) {
    __shared__ u16 t[32][33];
    const int z = blockIdx.z;
    const float* W = (z == 0) ? Wq : ((z == 1) ? Wk : Wv);
    u16* dst = (z == 0) ? QKWT : ((z == 1) ? QKWT + 1024 * 1024 : WvT);
    const float scale = (z == 0) ? 0.03125f : 1.0f;  // fold 1/sqrt(1024) into Wq
    const int bx = blockIdx.x * 32;  // n origin
    const int by = blockIdx.y * 32;  // k origin
    const int tx = threadIdx.x, ty = threadIdx.y;
    #pragma unroll
    for (int r = 0; r < 32; r += 8)
        t[ty + r][tx] = f2b(W[(size_t)(by + ty + r) * 1024 + bx + tx] * scale);
    __syncthreads();
    #pragma unroll
    for (int r = 0; r < 32; r += 8)
        dst[(size_t)(bx + ty + r) * 1024 + (by + tx)] = t[tx][ty + r];
}

// ============================================================================
// m201-style 8-phase NT GEMM.  C = A (MxK) * B^T, B stored [N][K].
//   BM=256, BN=NB*64 (NB=4 -> 256, NB=2 -> 128), BK=64. 512 thr = 8 waves 2Mx4N.
//   LDS: 2 buffers x {A0,A1[,B0[,B1]]} 16KB regions; st_16x32 XOR swizzle
//   (byte ^= ((row&4))<<3) applied on ds_read AND inverted on the per-lane
//   global source (DMA dest stays linear -- rule 21).
//   Per phase: {ds_read subtile || stage half-tile} -> s_barrier ->
//   setprio(1) 16(NB4)/8(NB2) MFMA setprio(0) -> s_barrier.
//   vmcnt(NB) only at phases 3 and 7; never 0 in steady state.
// EPI 0: C bf16 = acc ; EPI 2: causal exp + row sums ; EPI 3: fp32 acc/lrow
// Requires Kloc % 128 == 0 (NPAIR >= 2... >=1 handled, min used is 2).
// ============================================================================
template<int NB, int EPI>
__device__ __forceinline__ void gemm8p(
    char* __restrict__ sm,
    const u16* __restrict__ A, int lda,
    const u16* __restrict__ B, int ldb,
    char* __restrict__ Cb, int ldc,
    int m0, int n0, int Kloc, float* __restrict__ lrow)
{
    constexpr int BREG  = NB / 2;                  // B 16KB-regions per buffer
    constexpr int BUFSZ = (2 + BREG) * 16384;      // bytes per buffer
    constexpr int BOFF  = 2 * 16384;
    constexpr int WVM   = NB;                      // loads kept in flight at waits

    const int tid  = threadIdx.x;
    const int lane = tid & 63, wave = tid >> 6;
    const int wm = wave >> 2, wn = wave & 3;
    const int fl = lane & 15, fh = lane >> 4;

    // swizzled per-lane read offset within a 16KB region ([128 rows][128B])
    const int lane_off = (fl * 128 + fh * 16) ^ ((fl & 4) << 3);

    // staging: thread covers chunks idx=tid (rows 0..63) and idx=tid+512
    // (rows 64..127) of each region; global col pre-swizzled (involution).
    const int rr0 = tid >> 3;                                  // 0..63
    const int kc  = ((tid & 7) * 8) ^ ((rr0 & 4) << 2);        // elems
    const u16* sA0a = A + (size_t)(m0 + rr0) * lda + kc;
    const u16* sA0b = A + (size_t)(m0 + rr0 + 64) * lda + kc;
    const u16* sA1a = sA0a + (size_t)128 * lda;
    const u16* sA1b = sA0b + (size_t)128 * lda;
    const u16* sB0a = B + (size_t)(n0 + rr0) * ldb + kc;
    const u16* sB0b = B + (size_t)(n0 + rr0 + 64) * ldb + kc;
    const u16* sB1a = sB0a + (size_t)128 * ldb;    // used only when NB==4
    const u16* sB1b = sB0b + (size_t)128 * ldb;

    auto st = [&](const u16* s0, const u16* s1, int reg, int t) {
        u16* d = (u16*)(void*)(sm + (size_t)(t & 1) * BUFSZ + reg * 16384)
                 + wave * 512;
        gl2lds16(s0 + (size_t)t * 64, d);
        gl2lds16(s1 + (size_t)t * 64, d + 4096);
    };

    const f32x4 vzero = {0.f, 0.f, 0.f, 0.f};
    f32x4 acc[8][NB];
    #pragma unroll
    for (int i = 0; i < 8; ++i)
        #pragma unroll
        for (int j = 0; j < NB; ++j) acc[i][j] = vzero;

    const int NT = Kloc >> 6;
    const int NPAIR = NT >> 1;

    // prologue: B(0), A0(0), A1(0), B(1); tile0 resident, B(1) in flight
    st(sB0a, sB0b, 2, 0);
    if constexpr (NB == 4) st(sB1a, sB1b, 3, 0);
    st(sA0a, sA0b, 0, 0);
    st(sA1a, sA1b, 1, 0);
    st(sB0a, sB0b, 2, 1);
    if constexpr (NB == 4) st(sB1a, sB1b, 3, 1);
    waitvm<WVM>();
    bar();

    bf16x8 bfrag[NB][2];
    for (int pr = 0; pr < NPAIR; ++pr) {
        const int t0 = pr * 2;
        const bool last = (pr == NPAIR - 1);

        auto phase = [&](auto phc) {
            constexpr int PH = decltype(phc)::value;
            constexpr int q = PH & 3;            // C-quadrant (mt pair)
            constexpr int b = PH >> 2;           // tile t0+b lives in buf b
            // ---- ds_read register subtile (B once per tile, A per phase)
            if constexpr (q == 0) {
                #pragma unroll
                for (int nt = 0; nt < NB; ++nt)
                    #pragma unroll
                    for (int kk = 0; kk < 2; ++kk)
                        bfrag[nt][kk] = *(const bf16x8*)(sm + b * BUFSZ + BOFF
                            + wn * (NB * 2048) + nt * 2048 + kk * 64 + lane_off);
            }
            bf16x8 af[2][2];
            #pragma unroll
            for (int i = 0; i < 2; ++i)
                #pragma unroll
                for (int kk = 0; kk < 2; ++kk)
                    af[i][kk] = *(const bf16x8*)(sm + b * BUFSZ + wm * 16384
                        + (q * 2 + i) * 2048 + kk * 64 + lane_off);
            // ---- stage slot(s): region overwritten >=1 barrier-pair after
            //      its last read (A-odd@0, B-next@1/2, A-even@4/5, B-next@6/7)
            if constexpr (PH == 0) { st(sA0a, sA0b, 0, t0 + 1);
                                     st(sA1a, sA1b, 1, t0 + 1); }
            if constexpr (PH == 1) { if (!last) st(sB0a, sB0b, 2, t0 + 2); }
            if constexpr (PH == 2 && NB == 4) { if (!last) st(sB1a, sB1b, 3, t0 + 2); }
            if constexpr (PH == 4) { if (!last) st(sA0a, sA0b, 0, t0 + 2); }
            if constexpr (PH == 5) { if (!last) st(sA1a, sA1b, 1, t0 + 2); }
            if constexpr (PH == 6) { if (!last) st(sB0a, sB0b, 2, t0 + 3); }
            if constexpr (PH == 7 && NB == 4) { if (!last) st(sB1a, sB1b, 3, t0 + 3); }
            // ---- counted vmcnt, only twice per pair
            if constexpr (PH == 3) { if (last) waitvm<0>(); else waitvm<WVM>(); }
            if constexpr (PH == 7) { if (!last) waitvm<WVM>(); }
            bar();
            __builtin_amdgcn_s_setprio(1);
            #pragma unroll
            for (int i = 0; i < 2; ++i)
                #pragma unroll
                for (int nt = 0; nt < NB; ++nt)
                    #pragma unroll
                    for (int kk = 0; kk < 2; ++kk)
                        acc[q * 2 + i][nt] = __builtin_amdgcn_mfma_f32_16x16x32_bf16(
                            af[i][kk], bfrag[nt][kk], acc[q * 2 + i][nt], 0, 0, 0);
            __builtin_amdgcn_s_setprio(0);
            bar();
        };
        phase(std::integral_constant<int, 0>{});
        phase(std::integral_constant<int, 1>{});
        phase(std::integral_constant<int, 2>{});
        phase(std::integral_constant<int, 3>{});
        phase(std::integral_constant<int, 4>{});
        phase(std::integral_constant<int, 5>{});
        phase(std::integral_constant<int, 6>{});
        phase(std::integral_constant<int, 7>{});
    }

    const int rbase = m0 + wm * 128 + fh * 4;
    const int cbase = n0 + wn * (NB * 16) + fl;
    if constexpr (EPI == 0) {
        u16* Cp = (u16*)Cb;
        #pragma unroll
        for (int mt = 0; mt < 8; ++mt)
            #pragma unroll
            for (int nt = 0; nt < NB; ++nt)
                #pragma unroll
                for (int r = 0; r < 4; ++r)
                    Cp[(size_t)(rbase + mt * 16 + r) * ldc + cbase + nt * 16] =
                        f2b(acc[mt][nt][r]);
    } else if constexpr (EPI == 2) {
        u16* Cp = (u16*)Cb;
        #pragma unroll
        for (int mt = 0; mt < 8; ++mt)
            #pragma unroll
            for (int r = 0; r < 4; ++r) {
                const int row = rbase + mt * 16 + r;
                float part = 0.f;
                #pragma unroll
                for (int nt = 0; nt < NB; ++nt) {
                    const int col = cbase + nt * 16;
                    float p = (col <= row) ? __expf(acc[mt][nt][r]) : 0.f;
                    part += p;
                    Cp[(size_t)row * ldc + col] = f2b(p);
                }
                #pragma unroll
                for (int off = 1; off < 16; off <<= 1)
                    part += __shfl_xor(part, off, 64);
                if (fl == 0) atomicAdd(lrow + row, part);
            }
    } else {
        float* Cp = (float*)Cb;
        #pragma unroll
        for (int mt = 0; mt < 8; ++mt)
            #pragma unroll
            for (int r = 0; r < 4; ++r) {
                const int row = rbase + mt * 16 + r;
                const float inv = 1.0f / lrow[row];
                #pragma unroll
                for (int nt = 0; nt < NB; ++nt)
                    Cp[(size_t)row * ldc + cbase + nt * 16] = acc[mt][nt][r] * inv;
            }
    }
}

// ---- merged projection dispatch: QK (256 blocks) + V^T (128 blocks) --------
__global__ __launch_bounds__(512, 2)
void proj_kernel(const u16* __restrict__ xb, const u16* __restrict__ QKWT,
                 const u16* __restrict__ WvT, u16* __restrict__ QK,
                 u16* __restrict__ Vt) {
    __shared__ __align__(16) char smem[131072];   // 2 x 64KB buffers
    // XCD-aware bijective swizzle (384 % 8 == 0)
    const int bid = ((int)blockIdx.x & 7) * 48 + ((int)blockIdx.x >> 3);
    const u16 *A, *B;
    char* C;
    int ldc, m0, n0;
    if (bid < 256) {             // QK: [8192][2048] = xb @ QKWT^T
        const int it = bid >> 3, jt = bid & 7;
        A = xb;  B = QKWT;  C = (char*)QK;  ldc = 2048;
        m0 = it * 256;  n0 = jt * 256;
    } else {                     // V^T: [1024][8192] = WvT @ xb^T
        const int b = bid - 256;
        const int it = b >> 5, jt = b & 31;
        A = WvT;  B = xb;  C = (char*)Vt;  ldc = 8192;
        m0 = it * 256;  n0 = jt * 256;
    }
    gemm8p<4, 0>(smem, A, 1024, B, 1024, C, ldc, m0, n0, 1024, nullptr);
}

// ---- scores: triangular 256^2 grid (36 x 4), P = exp(masked QK^T), sums ----
__global__ __launch_bounds__(512, 2)
void scores_kernel(const u16* __restrict__ QK, u16* __restrict__ P,
                   float* __restrict__ l) {
    __shared__ __align__(16) char smem[131072];
    const int t = blockIdx.x, z = blockIdx.y;
    int it = (int)((sqrtf(8.0f * t + 1.0f) - 1.0f) * 0.5f);
    while ((it + 1) * (it + 2) / 2 <= t) ++it;
    while (it * (it + 1) / 2 > t) --it;
    const int jt = t - it * (it + 1) / 2;
    const u16* Qz = QK + (size_t)z * 2048 * 2048;  // Q cols [0,1024)
    const u16* Kz = Qz + 1024;                     // K cols [1024,2048)
    u16* Pz = P + (size_t)z * 2048 * 2048;
    gemm8p<4, 2>(smem, Qz, 2048, Kz, 2048, (char*)Pz, 2048,
                 it * 256, jt * 256, 1024, l + (size_t)z * 2048);
}

// ---- output: O = (P/l) @ V, 256x128 tiles, 256 blocks, heavy-first ---------
__global__ __launch_bounds__(512, 2)
void out_kernel(const u16* __restrict__ P, const u16* __restrict__ Vt,
                float* __restrict__ out, float* __restrict__ l) {
    __shared__ __align__(16) char smem[98304];    // 2 x 48KB buffers (NB=2)
    const int jt = blockIdx.x;              // 0..7  (N = 1024 / 128)
    const int it = 7 - (int)blockIdx.y;     // heavy first (Kloc = (it+1)*256)
    const int z = blockIdx.z;
    gemm8p<2, 3>(smem, P + (size_t)z * 2048 * 2048, 2048,
                 Vt + (size_t)z * 2048, 8192,
                 (char*)(out + (size_t)z * 2048 * 1024), 1024,
                 it * 256, jt * 128, (it + 1) * 256, l + (size_t)z * 2048);
}

extern "C" void kernel_launch(void* const* d_in, const int* in_sizes, int n_in,
                              void* d_out, int out_size, void* d_ws, size_t ws_size,
                              hipStream_t stream) {
    (void)in_sizes; (void)n_in; (void)out_size; (void)ws_size;
    const float* x  = (const float*)d_in[0];
    const float* Wq = (const float*)d_in[1];
    const float* Wk = (const float*)d_in[2];
    const float* Wv = (const float*)d_in[3];
    float* out = (float*)d_out;

    const size_t MB = 1u << 20;
    char* ws = (char*)d_ws;
    u16* xb   = (u16*)(ws);              // [8192][1024] bf16       16 MB
    u16* QKWT = (u16*)(ws + 16 * MB);    // [2048][1024] (WqT*s | WkT) 4 MB
    u16* WvT  = (u16*)(ws + 20 * MB);    // [1024][1024]             2 MB
    u16* QK   = (u16*)(ws + 22 * MB);    // [8192][2048] (Q|K)      32 MB
    u16* Vt   = (u16*)(ws + 54 * MB);    // V^T [1024][8192]        16 MB
    u16* P    = (u16*)(ws + 70 * MB);    // exp(S) [4][2048][2048]  32 MB
    float* l  = (float*)(ws + 102 * MB); // row sums [4][2048]      32 KB

    hipMemsetAsync(l, 0, 8192 * sizeof(float), stream);
    convert_x_kernel<<<8192, 256, 0, stream>>>(x, xb);
    transpose_w_kernel<<<dim3(32, 32, 3), dim3(32, 8), 0, stream>>>(Wq, Wk, Wv, QKWT, WvT);

    proj_kernel<<<384, 512, 0, stream>>>(xb, QKWT, WvT, QK, Vt);
    scores_kernel<<<dim3(36, 4), 512, 0, stream>>>(QK, P, l);
    out_kernel<<<dim3(8, 8, 4), 512, 0, stream>>>(P, Vt, out, l);
}